// Round 1
// baseline (452.127 us; speedup 1.0000x reference)
//
#include <hip/hip_runtime.h>

typedef unsigned short u16;
typedef unsigned int   u32;
typedef __attribute__((ext_vector_type(8))) short bf16x8;   // 8 bf16 (4 VGPRs)
typedef __attribute__((ext_vector_type(4))) float f32x4;    // mfma acc

#define EPS 1e-5f
#define MFMA(a,b,c) __builtin_amdgcn_mfma_f32_16x16x32_bf16(a,b,c,0,0,0)

// ---- wbuf (fp32) element offsets ----
constexpr int OB_b1=0, OB_g1=64, OB_be1=128, OB_b2=192, OB_bm1=256, OB_w192=320,
              OB_bm2=384, OB_gn=448, OB_bn=512, OB_bg1=576, OB_bg2=640,
              OB_Wg1=704, OB_Wg2=8896, WB_TOT=12992;
// ---- frag buffer (u16/bf16) element offsets ----
// B-frag order: frag f=(ks*4+nt), element ((f*64)+lane)*8+j = W[ks*32+(lane>>4)*8+j][nt*16+(lane&15)]
constexpr int FR_Wm1=0;          // 24 frags (K=192) = 12288
constexpr int FR_Wm2=12288;      // 8 frags  (K=64)  = 4096
constexpr int FR_rel=16384;      // 7 rows x 80 (pad) = 560, alloc 576
constexpr int FR_W1 =16960;      // 32 frags (K=256) = 16384
constexpr int FR_W2 =33344;      // 8 frags  (K=64)  = 4096
constexpr int FR_TOT=37440;

__device__ __forceinline__ float bf2f(u32 u) { return __uint_as_float(u << 16); }
__device__ __forceinline__ u16 f2bf(float f) {
  u32 b = __float_as_uint(f);
  return (u16)((b + 0x7fffu + ((b >> 16) & 1u)) >> 16);  // RNE
}
__device__ __forceinline__ u32 fkey(float f) {  // monotone float->u32 (finite)
  u32 b = __float_as_uint(f);
  return (b & 0x80000000u) ? ~b : (b | 0x80000000u);
}

// ---- prep: fp32 misc into wbuf; swizzle weights into bf16 B-frag layout ----
__launch_bounds__(256)
__global__ void k_prep(const float* __restrict__ W1, const float* __restrict__ b1,
                       const float* __restrict__ g1, const float* __restrict__ be1,
                       const float* __restrict__ W2, const float* __restrict__ b2,
                       const float* __restrict__ rel_emb,
                       const float* __restrict__ Wm1, const float* __restrict__ bm1,
                       const float* __restrict__ Wm2, const float* __restrict__ bm2,
                       const float* __restrict__ gn, const float* __restrict__ bn,
                       const float* __restrict__ Wg1, const float* __restrict__ bg1,
                       const float* __restrict__ Wg2, const float* __restrict__ bg2,
                       float* __restrict__ wbuf, u16* __restrict__ frags) {
  int tid = blockIdx.x * 256 + threadIdx.x;
  int nth = gridDim.x * 256;
  for (int i = tid; i < 64; i += nth) {
    wbuf[OB_b1 + i] = b1[i];   wbuf[OB_g1 + i] = g1[i];
    wbuf[OB_be1 + i] = be1[i]; wbuf[OB_b2 + i] = b2[i];
    wbuf[OB_bm1 + i] = bm1[i]; wbuf[OB_w192 + i] = Wm1[192 * 64 + i];
    wbuf[OB_bm2 + i] = bm2[i]; wbuf[OB_gn + i] = gn[i];
    wbuf[OB_bn + i] = bn[i];   wbuf[OB_bg1 + i] = bg1[i];
    wbuf[OB_bg2 + i] = bg2[i];
  }
  for (int i = tid; i < 8192; i += nth) wbuf[OB_Wg1 + i] = Wg1[i];
  for (int i = tid; i < 4096; i += nth) wbuf[OB_Wg2 + i] = Wg2[i];
  // swizzles: idx -> f=idx>>9, L=(idx>>3)&63, j=idx&7
  for (int idx = tid; idx < 16384; idx += nth) {
    int f = idx >> 9, L = (idx >> 3) & 63, j = idx & 7;
    int k = (f >> 2) * 32 + ((L >> 4) << 3) + j, n = ((f & 3) << 4) + (L & 15);
    frags[FR_W1 + idx] = f2bf(W1[k * 64 + n]);
  }
  for (int idx = tid; idx < 4096; idx += nth) {
    int f = idx >> 9, L = (idx >> 3) & 63, j = idx & 7;
    int k = (f >> 2) * 32 + ((L >> 4) << 3) + j, n = ((f & 3) << 4) + (L & 15);
    frags[FR_W2 + idx] = f2bf(W2[k * 64 + n]);
  }
  for (int idx = tid; idx < 12288; idx += nth) {
    int f = idx >> 9, L = (idx >> 3) & 63, j = idx & 7;
    int k = (f >> 2) * 32 + ((L >> 4) << 3) + j, n = ((f & 3) << 4) + (L & 15);
    frags[FR_Wm1 + idx] = f2bf(Wm1[k * 64 + n]);
  }
  for (int idx = tid; idx < 4096; idx += nth) {
    int f = idx >> 9, L = (idx >> 3) & 63, j = idx & 7;
    int k = (f >> 2) * 32 + ((L >> 4) << 3) + j, n = ((f & 3) << 4) + (L & 15);
    frags[FR_Wm2 + idx] = f2bf(Wm2[k * 64 + n]);
  }
  for (int idx = tid; idx < 576; idx += nth) {
    int r = idx / 80, c = idx % 80;
    frags[FR_rel + idx] = (r < 7 && c < 64) ? f2bf(rel_emb[r * 64 + c]) : (u16)0;
  }
}

// ---- stage A (MFMA): h = relu(relu(LN(X@W1+b1)) @ W2 + b2) -> bf16 ----
__launch_bounds__(256, 3)
__global__ void k_h(const float* __restrict__ X, const float* __restrict__ wbuf,
                    const u16* __restrict__ frags, u16* __restrict__ hb, int N) {
  __shared__ __align__(16) u16 sW1[32 * 512];
  __shared__ __align__(16) u16 sW2[8 * 512];
  __shared__ __align__(16) u16 st[4][16 * 72];

  // preload W1/W2 frags (20480 el = 2560 uint4)
  {
    const uint4* srcp = (const uint4*)(frags + FR_W1);
    uint4* d1 = (uint4*)sW1;
    for (int i = threadIdx.x; i < 2048; i += 256) d1[i] = srcp[i];
    const uint4* srcp2 = (const uint4*)(frags + FR_W2);
    uint4* d2 = (uint4*)sW2;
    for (int i = threadIdx.x; i < 512; i += 256) d2[i] = srcp2[i];
  }
  __syncthreads();

  int lane = threadIdx.x & 63, wave = threadIdx.x >> 6;
  int m = lane & 15, quad = lane >> 4, koff = quad * 8, col0 = m;

  float b1v[4], g1v[4], be1v[4], b2v[4];
  #pragma unroll
  for (int nt = 0; nt < 4; nt++) {
    int c = nt * 16 + col0;
    b1v[nt] = wbuf[OB_b1 + c]; g1v[nt] = wbuf[OB_g1 + c];
    be1v[nt] = wbuf[OB_be1 + c]; b2v[nt] = wbuf[OB_b2 + c];
  }

  int ntiles = (N + 15) / 16;
  int wid = blockIdx.x * 4 + wave, nw = gridDim.x * 4;
  for (int tile = wid; tile < ntiles; tile += nw) {
    int n0 = tile * 16;
    int nm = min(n0 + m, N - 1);
    const float* xr = X + (size_t)nm * 256 + koff;

    f32x4 acc[4] = {};
    #pragma unroll 1
    for (int ks = 0; ks < 8; ks++) {
      float4 u0 = *(const float4*)(xr + ks * 32);
      float4 u1 = *(const float4*)(xr + ks * 32 + 4);
      bf16x8 a;
      a[0] = (short)f2bf(u0.x); a[1] = (short)f2bf(u0.y);
      a[2] = (short)f2bf(u0.z); a[3] = (short)f2bf(u0.w);
      a[4] = (short)f2bf(u1.x); a[5] = (short)f2bf(u1.y);
      a[6] = (short)f2bf(u1.z); a[7] = (short)f2bf(u1.w);
      #pragma unroll
      for (int nt = 0; nt < 4; nt++) {
        bf16x8 b = *(const bf16x8*)(sW1 + (ks * 4 + nt) * 512 + lane * 8);
        acc[nt] = MFMA(a, b, acc[nt]);
      }
    }

    // + b1, LayerNorm over 64 cols of each row (rows = quad*4+r, 16-lane groups)
    float v[4][4];
    #pragma unroll
    for (int nt = 0; nt < 4; nt++)
      #pragma unroll
      for (int r = 0; r < 4; r++) v[nt][r] = acc[nt][r] + b1v[nt];

    #pragma unroll
    for (int r = 0; r < 4; r++) {
      float s = v[0][r] + v[1][r] + v[2][r] + v[3][r];
      #pragma unroll
      for (int mk = 8; mk >= 1; mk >>= 1) s += __shfl_xor(s, mk, 64);
      float mu = s * (1.f / 64.f);
      float q = 0.f;
      #pragma unroll
      for (int nt = 0; nt < 4; nt++) { float d = v[nt][r] - mu; q += d * d; }
      #pragma unroll
      for (int mk = 8; mk >= 1; mk >>= 1) q += __shfl_xor(q, mk, 64);
      float rs = rsqrtf(q * (1.f / 64.f) + EPS);
      #pragma unroll
      for (int nt = 0; nt < 4; nt++) {
        float h1 = fmaxf(fmaf((v[nt][r] - mu) * rs, g1v[nt], be1v[nt]), 0.f);
        st[wave][(quad * 4 + r) * 72 + nt * 16 + col0] = f2bf(h1);
      }
    }
    __builtin_amdgcn_wave_barrier();

    f32x4 acc2[4] = {};
    #pragma unroll
    for (int ks = 0; ks < 2; ks++) {
      bf16x8 a2 = *(const bf16x8*)(st[wave] + m * 72 + ks * 32 + koff);
      #pragma unroll
      for (int nt = 0; nt < 4; nt++) {
        bf16x8 b = *(const bf16x8*)(sW2 + (ks * 4 + nt) * 512 + lane * 8);
        acc2[nt] = MFMA(a2, b, acc2[nt]);
      }
    }
    __builtin_amdgcn_wave_barrier();

    #pragma unroll
    for (int nt = 0; nt < 4; nt++)
      #pragma unroll
      for (int r = 0; r < 4; r++) {
        int row = n0 + quad * 4 + r;
        if (row < N)
          hb[(size_t)row * 64 + nt * 16 + col0] = f2bf(fmaxf(acc2[nt][r] + b2v[nt], 0.f));
      }
  }
}

// ---- stage B+C (MFMA): edge MLP + coalesced atomic segment-sum ----
// 8-wave blocks share one weight-LDS copy (52.3 KB -> 3 blocks/CU = 24 waves/CU).
// Gathers for tile i+1 are issued BEFORE tile i's atomics so the vmcnt wait for
// the gathers never drains the in-flight atomics (counted wait, not vmcnt(0)).
__launch_bounds__(512, 6)
__global__ void k_edge(const float* __restrict__ te, const u16* __restrict__ hb,
                       const float* __restrict__ wbuf, const u16* __restrict__ frags,
                       float* __restrict__ agg, int E, int N) {
  __shared__ __align__(16) u16 sWm1[24 * 512];
  __shared__ __align__(16) u16 sWm2[8 * 512];
  __shared__ __align__(16) u16 srel[576];
  __shared__ __align__(16) u16 st[8][16 * 72];

  {
    const uint4* s1 = (const uint4*)(frags + FR_Wm1);
    uint4* d1 = (uint4*)sWm1;
    for (int i = threadIdx.x; i < 1536; i += 512) d1[i] = s1[i];
    const uint4* s2 = (const uint4*)(frags + FR_Wm2);
    uint4* d2 = (uint4*)sWm2;
    for (int i = threadIdx.x; i < 512; i += 512) d2[i] = s2[i];
    const uint4* s3 = (const uint4*)(frags + FR_rel);
    uint4* d3 = (uint4*)srel;
    for (int i = threadIdx.x; i < 72; i += 512) d3[i] = s3[i];
  }
  __syncthreads();

  int lane = threadIdx.x & 63, wave = threadIdx.x >> 6;
  int m = lane & 15, quad = lane >> 4, koff = quad * 8, col0 = m;

  float bm1v[4], w192v[4], bm2v[4];
  #pragma unroll
  for (int nt = 0; nt < 4; nt++) {
    int c = nt * 16 + col0;
    bm1v[nt] = wbuf[OB_bm1 + c];
    w192v[nt] = wbuf[OB_w192 + c];
    bm2v[nt] = wbuf[OB_bm2 + c];
  }

  int ntiles = (E + 15) / 16;
  int wid = blockIdx.x * 8 + wave, nw = gridDim.x * 8;

  int tile = wid;
  int src = 0, dstv = 0, rel = 0; float w = 0.f;
  bf16x8 af[6];

  if (tile < ntiles) {  // prologue: gather tile 0
    if (lane < 16) {
      int e = min(tile * 16 + lane, E - 1);
      float4 v = *(const float4*)(te + (size_t)e * 4);
      src  = min(max((int)v.x, 0), N - 1);
      dstv = min(max((int)v.y, 0), N - 1);
      rel  = min(max((int)v.z, 0), 6);
      w = v.w;
    }
    int sm = __shfl(src, m, 64), dm = __shfl(dstv, m, 64), rm = __shfl(rel, m, 64);
    const u16* hs = hb + (size_t)sm * 64;
    const u16* hd = hb + (size_t)dm * 64;
    af[0] = *(const bf16x8*)(hs + koff);
    af[1] = *(const bf16x8*)(hs + 32 + koff);
    af[2] = *(const bf16x8*)(hd + koff);
    af[3] = *(const bf16x8*)(hd + 32 + koff);
    af[4] = *(const bf16x8*)(srel + rm * 80 + koff);
    af[5] = *(const bf16x8*)(srel + rm * 80 + 32 + koff);
  }

  while (tile < ntiles) {
    int e0 = tile * 16;
    int tile_n = tile + nw;

    // ---- MFMA1 on current tile (waits on current gathers) ----
    f32x4 acc[4] = {};
    #pragma unroll
    for (int ks = 0; ks < 6; ks++)
      #pragma unroll
      for (int nt = 0; nt < 4; nt++) {
        bf16x8 b = *(const bf16x8*)(sWm1 + (ks * 4 + nt) * 512 + lane * 8);
        acc[nt] = MFMA(af[ks], b, acc[nt]);
      }

    // keep current tile's scatter state before prefetch clobbers it
    int dstc = dstv; float wc = w;

    // ---- prefetch next tile: te load + hb gathers (reuse af regs) ----
    if (tile_n < ntiles) {
      if (lane < 16) {
        int e = min(tile_n * 16 + lane, E - 1);
        float4 v = *(const float4*)(te + (size_t)e * 4);
        src  = min(max((int)v.x, 0), N - 1);
        dstv = min(max((int)v.y, 0), N - 1);
        rel  = min(max((int)v.z, 0), 6);
        w = v.w;
      }
      int sm = __shfl(src, m, 64), dm = __shfl(dstv, m, 64), rm = __shfl(rel, m, 64);
      const u16* hs = hb + (size_t)sm * 64;
      const u16* hd = hb + (size_t)dm * 64;
      af[0] = *(const bf16x8*)(hs + koff);
      af[1] = *(const bf16x8*)(hs + 32 + koff);
      af[2] = *(const bf16x8*)(hd + koff);
      af[3] = *(const bf16x8*)(hd + 32 + koff);
      af[4] = *(const bf16x8*)(srel + rm * 80 + koff);
      af[5] = *(const bf16x8*)(srel + rm * 80 + 32 + koff);
    }

    // ---- epilogue 1: + bm1 + w*Wm1[192], relu, stage t in LDS (bf16) ----
    float wrow[4];
    #pragma unroll
    for (int r = 0; r < 4; r++) wrow[r] = __shfl(wc, quad * 4 + r, 64);
    #pragma unroll
    for (int nt = 0; nt < 4; nt++)
      #pragma unroll
      for (int r = 0; r < 4; r++) {
        float v = fmaf(wrow[r], w192v[nt], acc[nt][r] + bm1v[nt]);
        st[wave][(quad * 4 + r) * 72 + nt * 16 + col0] = f2bf(fmaxf(v, 0.f));
      }
    __builtin_amdgcn_wave_barrier();

    f32x4 acc2[4] = {};
    #pragma unroll
    for (int ks = 0; ks < 2; ks++) {
      bf16x8 a2 = *(const bf16x8*)(st[wave] + m * 72 + ks * 32 + koff);
      #pragma unroll
      for (int nt = 0; nt < 4; nt++) {
        bf16x8 b = *(const bf16x8*)(sWm2 + (ks * 4 + nt) * 512 + lane * 8);
        acc2[nt] = MFMA(a2, b, acc2[nt]);
      }
    }
    __builtin_amdgcn_wave_barrier();

    // ---- scatter: + bm2, coalesced atomics (16 consecutive floats/row) ----
    // issued after next tile's gathers -> atomics stay in flight across tiles
    #pragma unroll
    for (int r = 0; r < 4; r++) {
      int row = quad * 4 + r;
      int dr = __shfl(dstc, row, 64);
      if (e0 + row < E) {
        #pragma unroll
        for (int nt = 0; nt < 4; nt++)
          atomicAdd(agg + (size_t)dr * 64 + nt * 16 + col0, acc2[nt][r] + bm2v[nt]);
      }
    }

    tile = tile_n;
  }
}

// ---- stage D1: nodes = LN(h+agg); global column sum + max ----
__launch_bounds__(256)
__global__ void k_nodes(const u16* __restrict__ hb, const float* __restrict__ agg,
                        const float* __restrict__ wbuf, float* __restrict__ gsum,
                        u32* __restrict__ gmax, int N) {
  int lane = threadIdx.x & 63, wave = threadIdx.x >> 6;
  int wid = blockIdx.x * 4 + wave;
  int nw = gridDim.x * 4;
  float gn = wbuf[OB_gn + lane], bn = wbuf[OB_bn + lane];
  float sj = 0.f, mj = -3.0e38f;
  for (int n = wid; n < N; n += nw) {
    float v = bf2f(hb[(size_t)n * 64 + lane]) + agg[(size_t)n * 64 + lane];
    float s = v;
    #pragma unroll
    for (int m = 32; m >= 1; m >>= 1) s += __shfl_xor(s, m, 64);
    float mu = s * (1.f / 64.f);
    float d = v - mu;
    float q = d * d;
    #pragma unroll
    for (int m = 32; m >= 1; m >>= 1) q += __shfl_xor(q, m, 64);
    float rs = rsqrtf(q * (1.f / 64.f) + EPS);
    float val = fmaf(d * rs, gn, bn);
    sj += val;
    mj = fmaxf(mj, val);
  }
  __shared__ float bs[256], bm[256];
  bs[threadIdx.x] = sj;
  bm[threadIdx.x] = mj;
  __syncthreads();
  if (threadIdx.x < 64) {
    int t = threadIdx.x;
    float ts = bs[t] + bs[64 + t] + bs[128 + t] + bs[192 + t];
    float tm = fmaxf(fmaxf(bm[t], bm[64 + t]), fmaxf(bm[128 + t], bm[192 + t]));
    atomicAdd(gsum + t, ts);
    atomicMax(gmax + t, fkey(tm));
  }
}

// ---- stage D2: g=[mean,max]; out = relu(g@Wg1+bg1)@Wg2+bg2 (fp32 out) ----
__launch_bounds__(128)
__global__ void k_final(const float* __restrict__ wbuf, const float* __restrict__ gsum,
                        const u32* __restrict__ gmax, float* __restrict__ out, int N) {
  __shared__ float g[128];
  __shared__ float y1[64];
  int t = threadIdx.x;
  if (t < 64) {
    g[t] = gsum[t] / (float)N;
  } else {
    u32 k = gmax[t - 64];
    u32 b = (k & 0x80000000u) ? (k & 0x7fffffffu) : ~k;
    g[t] = __uint_as_float(b);
  }
  __syncthreads();
  if (t < 64) {
    float a = wbuf[OB_bg1 + t];
    for (int i = 0; i < 128; i++) a = fmaf(g[i], wbuf[OB_Wg1 + i * 64 + t], a);
    y1[t] = fmaxf(a, 0.f);
  }
  __syncthreads();
  if (t < 64) {
    float a = wbuf[OB_bg2 + t];
    for (int k = 0; k < 64; k++) a = fmaf(y1[k], wbuf[OB_Wg2 + k * 64 + t], a);
    out[t] = a;
  }
}

extern "C" void kernel_launch(void* const* d_in, const int* in_sizes, int n_in,
                              void* d_out, int out_size, void* d_ws, size_t ws_size,
                              hipStream_t stream) {
  const int N = in_sizes[0] / 256;
  const int E = in_sizes[1] / 4;

  char* ws = (char*)d_ws;
  size_t aggB = (size_t)N * 64 * 4;
  size_t hbB  = (size_t)N * 64 * 2;
  float* agg   = (float*)ws;
  u16*   hb    = (u16*)(ws + aggB);
  float* gsum  = (float*)(ws + aggB + hbB);        // 64 f32
  u32*   gmax  = (u32*)(ws + aggB + hbB + 256);    // 64 u32
  float* wbuf  = (float*)(ws + aggB + hbB + 512);
  u16*   frags = (u16*)(ws + aggB + hbB + 512 + (size_t)WB_TOT * 4);

  const float* X  = (const float*)d_in[0];
  const float* te = (const float*)d_in[1];

  hipLaunchKernelGGL(k_prep, dim3(64), dim3(256), 0, stream,
                     (const float*)d_in[2], (const float*)d_in[3], (const float*)d_in[4],
                     (const float*)d_in[5], (const float*)d_in[6], (const float*)d_in[7],
                     (const float*)d_in[8], (const float*)d_in[9], (const float*)d_in[10],
                     (const float*)d_in[11], (const float*)d_in[12], (const float*)d_in[13],
                     (const float*)d_in[14], (const float*)d_in[15], (const float*)d_in[16],
                     (const float*)d_in[17], (const float*)d_in[18], wbuf, frags);
  hipMemsetAsync(agg, 0, aggB, stream);
  hipMemsetAsync(gsum, 0, 512, stream);
  hipLaunchKernelGGL(k_h, dim3(640), dim3(256), 0, stream, X, wbuf, frags, hb, N);
  hipLaunchKernelGGL(k_edge, dim3(768), dim3(512), 0, stream, te, hb, wbuf, frags, agg, E, N);
  hipLaunchKernelGGL(k_nodes, dim3(2048), dim3(256), 0, stream, hb, agg, wbuf, gsum, gmax, N);
  hipLaunchKernelGGL(k_final, dim3(1), dim3(128), 0, stream, wbuf, gsum, gmax, (float*)d_out, N);
}